// Round 17
// baseline (64.759 us; speedup 1.0000x reference)
//
#include <hip/hip_runtime.h>
#include <hip/hip_bf16.h>
#include <math.h>

#define N_NODES 1024
#define D_DIM   128
#define H_HEADS 8
#define DH      1024   // D*H

typedef short  short8 __attribute__((ext_vector_type(8)));
typedef float  f32x16 __attribute__((ext_vector_type(16)));
typedef float  f32x4  __attribute__((ext_vector_type(4)));

static __device__ __forceinline__ unsigned short f2bf(float x) {
    __hip_bfloat16 h = __float2bfloat16(x);
    return *reinterpret_cast<unsigned short*>(&h);
}
// pure value ops (no volatile — R16: volatile blocked load hoisting)
static __device__ __forceinline__ unsigned cvt_pk_bf16(float lo, float hi) {
    unsigned r;
    asm("v_cvt_pk_bf16_f32 %0, %1, %2" : "=v"(r) : "v"(lo), "v"(hi));
    return r;
}
static __device__ __forceinline__ void permlane32_swap(unsigned &a, unsigned &b) {
    asm("v_permlane32_swap_b32 %0, %1" : "+v"(a), "+v"(b));
}
// raw hardware exp2 (single TRANS instr; avoids OCML range-fixup tail)
static __device__ __forceinline__ float fast_exp2(float x) {
    float r;
    asm("v_exp_f32 %0, %1" : "=v"(r) : "v"(x));
    return r;
}

// ---------------------------------------------------------------------------
// Kernel 1: prep (1824 blocks): [0,768) QKV MFMA | [768,1792) bias gather |
// [1792,1824) Wo hi/lo split.  (R13-R16 proven, unchanged)
// ---------------------------------------------------------------------------
__global__ __launch_bounds__(256, 1) void prep_kernel(
        const float* __restrict__ x,  const float* __restrict__ Wq,
        const float* __restrict__ Wk, const float* __restrict__ Wv,
        const float* __restrict__ sp, const float* __restrict__ ed,
        const float* __restrict__ Wo,
        unsigned short* __restrict__ Qb, unsigned short* __restrict__ Kb,
        unsigned short* __restrict__ Vb, unsigned short* __restrict__ Bq16,
        unsigned short* __restrict__ Woh, unsigned short* __restrict__ Wol) {
    __shared__ float tile[32][33];
    const int u   = blockIdx.x;
    const int tid = threadIdx.x;

    if (u < 768) {
        const int lane = tid & 63, wvi = tid >> 6;
        const int l31 = lane & 31, hi = lane >> 5;
        const int m   = u >> 8;
        const int rem = u & 255;
        const int rb0 = (rem & 7) * 128 + wvi * 32;
        const int col = (rem >> 3) * 32 + l31;
        const float* W        = (m == 0) ? Wq : (m == 1) ? Wk : Wv;
        unsigned short* Out   = (m == 0) ? Qb : (m == 1) ? Kb : Vb;
        const float osc = (m == 0) ? 0.12751879523173864f : 1.0f; // 128^-0.5*log2e

        const float* xrow = x + (size_t)(rb0 + l31) * 128 + 8 * hi;
        const float* wrow = W + (size_t)col * 128 + 8 * hi;

        f32x16 acc = {};
        #pragma unroll
        for (int ks = 0; ks < 8; ++ks) {
            float4 xa = *reinterpret_cast<const float4*>(xrow + ks * 16);
            float4 xb = *reinterpret_cast<const float4*>(xrow + ks * 16 + 4);
            float4 wa = *reinterpret_cast<const float4*>(wrow + ks * 16);
            float4 wb = *reinterpret_cast<const float4*>(wrow + ks * 16 + 4);
            union { short8 s8; unsigned uu[4]; } af, bf;
            af.uu[0] = cvt_pk_bf16(xa.x, xa.y); af.uu[1] = cvt_pk_bf16(xa.z, xa.w);
            af.uu[2] = cvt_pk_bf16(xb.x, xb.y); af.uu[3] = cvt_pk_bf16(xb.z, xb.w);
            bf.uu[0] = cvt_pk_bf16(wa.x, wa.y); bf.uu[1] = cvt_pk_bf16(wa.z, wa.w);
            bf.uu[2] = cvt_pk_bf16(wb.x, wb.y); bf.uu[3] = cvt_pk_bf16(wb.z, wb.w);
            acc = __builtin_amdgcn_mfma_f32_32x32x16_bf16(af.s8, bf.s8, acc, 0, 0, 0);
        }
        #pragma unroll
        for (int i = 0; i < 16; ++i) {
            int mm = (i & 3) + 8 * (i >> 2) + 4 * hi;
            Out[(size_t)(rb0 + mm) * DH + col] = f2bf(acc[i] * osc);
        }
    } else if (u < 1792) {
        const int b2 = u - 768;
        const int cb = b2 & 31, rb = b2 >> 5;
        const float L2E = 1.4426950408889634f;
        for (int i = tid; i < 1024; i += 256) {
            int rr = i >> 5, cc = i & 31;
            size_t g = (size_t)(rb * 32 + rr) * 1024 + cb * 32 + cc;
            tile[rr][cc] = (sp[g] + ed[g]) * L2E;
        }
        __syncthreads();
        // scatter in MFMA-fragment order as bf16: thread -> (rr, hi, j-group of 4)
        const int rr  = tid >> 3, rem = tid & 7;
        const int hi  = rem >> 2, g = rem & 3;
        const int c0  = 8 * g + 4 * hi;
        uint2 v;
        v.x = cvt_pk_bf16(tile[rr][c0],     tile[rr][c0 + 1]);
        v.y = cvt_pk_bf16(tile[rr][c0 + 2], tile[rr][c0 + 3]);
        reinterpret_cast<uint2*>(Bq16)[((size_t)(cb * 2 + hi) * 1024 + rb * 32 + rr) * 4 + g] = v;
    } else {
        const int b2 = u - 1792;                   // 0..31
        const size_t base = (size_t)b2 * 4096 + (size_t)tid * 16;
        #pragma unroll
        for (int t = 0; t < 4; ++t) {
            float4 w = *reinterpret_cast<const float4*>(Wo + base + t * 4);
            float ww[4] = { w.x, w.y, w.z, w.w };
            unsigned short h4[4], l4[4];
            #pragma unroll
            for (int j = 0; j < 4; ++j) {
                unsigned uv = __float_as_uint(ww[j]);
                h4[j] = (unsigned short)(uv >> 16);
                l4[j] = f2bf(ww[j] - __uint_as_float(uv & 0xFFFF0000u));
            }
            *reinterpret_cast<uint2*>(Woh + base + t * 4) = *reinterpret_cast<uint2*>(h4);
            *reinterpret_cast<uint2*>(Wol + base + t * 4) = *reinterpret_cast<uint2*>(l4);
        }
    }
}

// ---------------------------------------------------------------------------
// helpers
// ---------------------------------------------------------------------------
// stage HALF of one slice's V^T (9 rows x 512 bf16, XOR(h<<4) swizzle + ones)
static __device__ __forceinline__ void stage_vt_half(const unsigned short* __restrict__ src,
                                                     char* base, int tid) {
    int pr = tid;                                   // c-pair 0..255 (512 cols)
    short8 v0 = *reinterpret_cast<const short8*>(src + (size_t)(2 * pr) * 8);
    short8 v1 = *reinterpret_cast<const short8*>(src + (size_t)(2 * pr + 1) * 8);
    #pragma unroll
    for (int h = 0; h < 8; ++h) {
        unsigned d = (unsigned)(unsigned short)v0[h] |
                     ((unsigned)(unsigned short)v1[h] << 16);
        *reinterpret_cast<unsigned*>(base + h * 1024 + ((4 * pr) ^ (h << 4))) = d;
    }
    reinterpret_cast<unsigned*>(base + 8 * 1024)[tid] = 0x3F803F80u;  // ones row
}

// 32B bf16 fragment-order bias load + expand to f32x16
static __device__ __forceinline__ f32x16 load_bias16(const uint4* b) {
    uint4 ua = b[0], ub = b[1];
    unsigned uu[8] = { ua.x, ua.y, ua.z, ua.w, ub.x, ub.y, ub.z, ub.w };
    f32x16 o;
    #pragma unroll
    for (int i = 0; i < 8; ++i) {
        o[2 * i]     = __uint_as_float(uu[i] << 16);
        o[2 * i + 1] = __uint_as_float(uu[i] & 0xFFFF0000u);
    }
    return o;
}

static __device__ __forceinline__ void pack_p(const float* p, short8& pb1, short8& pb2) {
    unsigned u0 = cvt_pk_bf16(p[0],  p[1]);
    unsigned u1 = cvt_pk_bf16(p[2],  p[3]);
    unsigned u2 = cvt_pk_bf16(p[4],  p[5]);
    unsigned u3 = cvt_pk_bf16(p[6],  p[7]);
    unsigned u4 = cvt_pk_bf16(p[8],  p[9]);
    unsigned u5 = cvt_pk_bf16(p[10], p[11]);
    unsigned u6 = cvt_pk_bf16(p[12], p[13]);
    unsigned u7 = cvt_pk_bf16(p[14], p[15]);
    permlane32_swap(u0, u2);
    permlane32_swap(u1, u3);
    permlane32_swap(u4, u6);
    permlane32_swap(u5, u7);
    union { short8 s8; unsigned uu[4]; } a, b;
    a.uu[0] = u0; a.uu[1] = u1; a.uu[2] = u2; a.uu[3] = u3;
    b.uu[0] = u4; b.uu[1] = u5; b.uu[2] = u6; b.uu[3] = u7;
    pb1 = a.s8; pb2 = b.s8;
}

// ---------------------------------------------------------------------------
// Kernel 2: attention, 2 dd-slices/block (bias shared), kv-column-split x2.
// R17: re-applies ch-split on the NOW latency-bound structure (R16: VALU 49%,
// MFMA 11%, occupancy 17% -> idle issue slots). 1024 blocks, LDS 18.4 KB
// -> 4 blk/CU. Writes unnormalized f32 partials + partial lsum; exact
// combine pass follows.
// ---------------------------------------------------------------------------
__global__ __launch_bounds__(256, 1) void attn2_kernel(
        const unsigned short* __restrict__ Qb, const unsigned short* __restrict__ Kb,
        const unsigned short* __restrict__ Vb, const unsigned short* __restrict__ Bq16,
        float* __restrict__ Opart, float* __restrict__ Lpart) {
    __shared__ __align__(16) char smraw[18432];   // 2 x (9x512 bf16)
    const int tid = threadIdx.x;
    const int rbx = blockIdx.x, dp = blockIdx.y, ch = blockIdx.z;
    const int lane = tid & 63, wvi = tid >> 6;
    const int l31 = lane & 31, hi = lane >> 5;

    stage_vt_half(Vb + (size_t)(2 * dp) * 8192     + (size_t)ch * 4096, smraw,        tid);
    stage_vt_half(Vb + (size_t)(2 * dp + 1) * 8192 + (size_t)ch * 4096, smraw + 9216, tid);
    __syncthreads();

    const int r = rbx * 128 + wvi * 32 + l31;
    short8 qf0 = {}, qf1 = {};
    if (!hi) {
        qf0 = *reinterpret_cast<const short8*>(Qb + (size_t)(2 * dp)     * 8192 + (size_t)r * 8);
        qf1 = *reinterpret_cast<const short8*>(Qb + (size_t)(2 * dp + 1) * 8192 + (size_t)r * 8);
    }
    f32x16 o0 = {}, o1 = {};
    const unsigned short* kp0 = Kb + (size_t)(2 * dp) * 8192 + (size_t)(ch * 512 + l31) * 8;
    const unsigned short* kp1 = kp0 + 8192;
    // bias (bf16 frag-contig): global cb = ch*16 + local; per-local-step stride 4096 uint4
    const uint4* bp = reinterpret_cast<const uint4*>(Bq16)
                      + ((size_t)(ch * 32 + hi) * 1024 + r) * 2;
    const int vrow = (l31 < 8) ? l31 : 8;          // lanes 8..31 -> ones row
    const char* vb0 = smraw + vrow * 1024;
    const char* vb1 = smraw + 9216 + vrow * 1024;
    const int vswz = vrow << 4;

    auto step2 = [&](int cbv, const f32x16& bias, const short8& k0, const short8& k1) {
        f32x16 s0 = __builtin_amdgcn_mfma_f32_32x32x16_bf16(k0, qf0, bias, 0, 0, 0);
        f32x16 s1 = __builtin_amdgcn_mfma_f32_32x32x16_bf16(k1, qf1, bias, 0, 0, 0);
        // V loads early: latency hides under exp/pack
        short8 va1 = *reinterpret_cast<const short8*>(vb0 + ((cbv * 64 + 16 * hi)      ^ vswz));
        short8 va2 = *reinterpret_cast<const short8*>(vb0 + ((cbv * 64 + 32 + 16 * hi) ^ vswz));
        short8 vc1 = *reinterpret_cast<const short8*>(vb1 + ((cbv * 64 + 16 * hi)      ^ vswz));
        short8 vc2 = *reinterpret_cast<const short8*>(vb1 + ((cbv * 64 + 32 + 16 * hi) ^ vswz));
        float p0[16], p1[16];
        #pragma unroll
        for (int i = 0; i < 16; ++i) { p0[i] = fast_exp2(s0[i]); p1[i] = fast_exp2(s1[i]); }
        short8 pa1, pa2, pb1, pb2;
        pack_p(p0, pa1, pa2);
        pack_p(p1, pb1, pb2);
        o0 = __builtin_amdgcn_mfma_f32_32x32x16_bf16(va1, pa1, o0, 0, 0, 0);
        o1 = __builtin_amdgcn_mfma_f32_32x32x16_bf16(vc1, pb1, o1, 0, 0, 0);
        o0 = __builtin_amdgcn_mfma_f32_32x32x16_bf16(va2, pa2, o0, 0, 0, 0);
        o1 = __builtin_amdgcn_mfma_f32_32x32x16_bf16(vc2, pb2, o1, 0, 0, 0);
    };

    // 2x unrolled, double-buffered bias+K prefetch over 16 local c-blocks
    f32x16 bA = load_bias16(bp), bB = load_bias16(bp + 4096);
    short8 kA0 = *reinterpret_cast<const short8*>(kp0);
    short8 kA1 = *reinterpret_cast<const short8*>(kp1);
    short8 kB0 = *reinterpret_cast<const short8*>(kp0 + 256);
    short8 kB1 = *reinterpret_cast<const short8*>(kp1 + 256);
    for (int cb = 0; cb < 16; cb += 2) {
        step2(cb, bA, kA0, kA1);
        if (cb < 14) {
            bA  = load_bias16(bp + (size_t)(cb + 2) * 4096);
            kA0 = *reinterpret_cast<const short8*>(kp0 + (size_t)(cb + 2) * 256);
            kA1 = *reinterpret_cast<const short8*>(kp1 + (size_t)(cb + 2) * 256);
        }
        step2(cb + 1, bB, kB0, kB1);
        if (cb < 14) {
            bB  = load_bias16(bp + (size_t)(cb + 3) * 4096);
            kB0 = *reinterpret_cast<const short8*>(kp0 + (size_t)(cb + 3) * 256);
            kB1 = *reinterpret_cast<const short8*>(kp1 + (size_t)(cb + 3) * 256);
        }
    }

    // unnormalized partials: every lane's own oa[4] = this half's full lsum
    #pragma unroll
    for (int s = 0; s < 2; ++s) {
        const f32x16& oa = s ? o1 : o0;
        const int dd = 2 * dp + s;
        size_t off = (size_t)ch * 1048576 + (size_t)dd * 8192 + (size_t)r * 8 + 4 * hi;
        *reinterpret_cast<float4*>(Opart + off) = make_float4(oa[0], oa[1], oa[2], oa[3]);
        if (!hi) Lpart[(size_t)ch * 131072 + (size_t)dd * 1024 + r] = oa[4];
    }
}

// ---------------------------------------------------------------------------
// Kernel 3: combine halves: O = (O1+O2)/(l1+l2) -> single bf16 (exact f32).
// ---------------------------------------------------------------------------
__global__ __launch_bounds__(256) void combine_kernel(const float* __restrict__ Opart,
                                                      const float* __restrict__ Lpart,
                                                      unsigned short* __restrict__ Oh) {
    const int gid = blockIdx.x * 256 + threadIdx.x;        // 0..131071 = dd*1024+r
    const float4* p1 = reinterpret_cast<const float4*>(Opart) + (size_t)gid * 2;
    const float4* p2 = reinterpret_cast<const float4*>(Opart + 1048576) + (size_t)gid * 2;
    float4 a0 = p1[0], a1 = p1[1], b0 = p2[0], b1 = p2[1];
    const float rl = 1.f / (Lpart[gid] + Lpart[131072 + gid]);
    union { short8 s8; unsigned short us[8]; } h8;
    h8.us[0] = f2bf((a0.x + b0.x) * rl);
    h8.us[1] = f2bf((a0.y + b0.y) * rl);
    h8.us[2] = f2bf((a0.z + b0.z) * rl);
    h8.us[3] = f2bf((a0.w + b0.w) * rl);
    h8.us[4] = f2bf((a1.x + b1.x) * rl);
    h8.us[5] = f2bf((a1.y + b1.y) * rl);
    h8.us[6] = f2bf((a1.z + b1.z) * rl);
    h8.us[7] = f2bf((a1.w + b1.w) * rl);
    *reinterpret_cast<short8*>(Oh + (size_t)gid * 8) = h8.s8;
}

// ---------------------------------------------------------------------------
// Kernel 4: output projection, 16x16 MFMA, 2-term split (O single bf16):
// out = Oh*Wh + Oh*Wl.  (R13-R16 proven)
// ---------------------------------------------------------------------------
__global__ __launch_bounds__(256) void oproj_kernel(
        const unsigned short* __restrict__ Oh,
        const unsigned short* __restrict__ Woh, const unsigned short* __restrict__ Wol,
        float* __restrict__ out) {
    __shared__ float red[4][256];
    const int u = blockIdx.x, tid = threadIdx.x;
    const int lane = tid & 63, wvi = tid >> 6;
    const int l15 = lane & 15, kg = lane >> 4;
    const int rbase = (u & 63) * 16, cbase = (u >> 6) * 16;

    const unsigned short* ah_p = Oh  + (size_t)(rbase + l15) * 1024 + wvi * 256 + kg * 8;
    const unsigned short* bh_p = Woh + (size_t)(cbase + l15) * 1024 + wvi * 256 + kg * 8;
    const unsigned short* bl_p = Wol + (size_t)(cbase + l15) * 1024 + wvi * 256 + kg * 8;

    f32x4 acc = {};
    #pragma unroll
    for (int ks = 0; ks < 8; ++ks) {
        short8 ah = *reinterpret_cast<const short8*>(ah_p + ks * 32);
        short8 bh = *reinterpret_cast<const short8*>(bh_p + ks * 32);
        short8 bl = *reinterpret_cast<const short8*>(bl_p + ks * 32);
        acc = __builtin_amdgcn_mfma_f32_16x16x32_bf16(ah, bh, acc, 0, 0, 0);
        acc = __builtin_amdgcn_mfma_f32_16x16x32_bf16(ah, bl, acc, 0, 0, 0);
    }
    #pragma unroll
    for (int i = 0; i < 4; ++i)
        red[wvi][(kg * 4 + i) * 16 + l15] = acc[i];
    __syncthreads();
    float v = red[0][tid & 255] + red[1][tid & 255] + red[2][tid & 255] + red[3][tid & 255];
    out[(size_t)(rbase + (tid >> 4)) * D_DIM + cbase + (tid & 15)] = v;
}

// ---------------------------------------------------------------------------
extern "C" void kernel_launch(void* const* d_in, const int* in_sizes, int n_in,
                              void* d_out, int out_size, void* d_ws, size_t ws_size,
                              hipStream_t stream) {
    const float* x  = (const float*)d_in[0];
    const float* sp = (const float*)d_in[1];
    const float* ed = (const float*)d_in[2];
    const float* Wq = (const float*)d_in[3];
    const float* Wk = (const float*)d_in[4];
    const float* Wv = (const float*)d_in[5];
    const float* Wo = (const float*)d_in[6];
    float* out = (float*)d_out;

    float* ws = (float*)d_ws;
    const size_t M = (size_t)N_NODES * DH;               // 1M elements
    unsigned short* Bq16 = (unsigned short*)ws;          // 2 MB bf16 (frag-contig, *log2e)
    unsigned short* Qb = Bq16 + M;                       // 2 MB bf16 each
    unsigned short* Kb = Qb + M;
    unsigned short* Vb = Kb + M;
    unsigned short* Oh = Vb + M;                         // attn out, bf16 (2 MB)
    unsigned short* Woh = Oh + M;                        // 128x1024 bf16 each
    unsigned short* Wol = Woh + 131072;
    float* Opart = (float*)(Wol + 131072);               // 2 x 1M f32 partial O (8 MB)
    float* Lpart = Opart + 2 * M;                        // 2 x 128K f32 partial lsum
                                                         // total ~19.5 MB

    prep_kernel<<<dim3(1824), 256, 0, stream>>>(x, Wq, Wk, Wv, sp, ed, Wo,
                                                Qb, Kb, Vb, Bq16, Woh, Wol);
    attn2_kernel<<<dim3(8, 64, 2), 256, 0, stream>>>(Qb, Kb, Vb, Bq16, Opart, Lpart);
    combine_kernel<<<dim3(512), 256, 0, stream>>>(Opart, Lpart, Oh);
    oproj_kernel<<<dim3(512), 256, 0, stream>>>(Oh, Woh, Wol, out);
}

// Round 18
// 61.200 us; speedup vs baseline: 1.0581x; 1.0581x over previous
//
#include <hip/hip_runtime.h>
#include <hip/hip_bf16.h>
#include <math.h>

#define N_NODES 1024
#define D_DIM   128
#define H_HEADS 8
#define DH      1024   // D*H

typedef short  short8 __attribute__((ext_vector_type(8)));
typedef float  f32x16 __attribute__((ext_vector_type(16)));
typedef float  f32x4  __attribute__((ext_vector_type(4)));

static __device__ __forceinline__ unsigned short f2bf(float x) {
    __hip_bfloat16 h = __float2bfloat16(x);
    return *reinterpret_cast<unsigned short*>(&h);
}
static __device__ __forceinline__ unsigned cvt_pk_bf16(float lo, float hi) {
    unsigned r;
    asm volatile("v_cvt_pk_bf16_f32 %0, %1, %2" : "=v"(r) : "v"(lo), "v"(hi));
    return r;
}
static __device__ __forceinline__ void permlane32_swap(unsigned &a, unsigned &b) {
    asm volatile("v_permlane32_swap_b32 %0, %1" : "+v"(a), "+v"(b));
}
// raw hardware exp2 (single TRANS instr; avoids OCML range-fixup tail)
static __device__ __forceinline__ float fast_exp2(float x) {
    float r;
    asm("v_exp_f32 %0, %1" : "=v"(r) : "v"(x));
    return r;
}

// ---------------------------------------------------------------------------
// Kernel 1: prep (1824 blocks): [0,768) QKV MFMA | [768,1792) bias gather |
// [1792,1824) Wo hi/lo split.   (R7-proven, verbatim)
// ---------------------------------------------------------------------------
__global__ __launch_bounds__(256) void prep_kernel(
        const float* __restrict__ x,  const float* __restrict__ Wq,
        const float* __restrict__ Wk, const float* __restrict__ Wv,
        const float* __restrict__ sp, const float* __restrict__ ed,
        const float* __restrict__ Wo,
        unsigned short* __restrict__ Qb, unsigned short* __restrict__ Kb,
        unsigned short* __restrict__ Vb, float* __restrict__ Bq,
        unsigned short* __restrict__ Woh, unsigned short* __restrict__ Wol) {
    __shared__ float tile[32][33];
    const int u   = blockIdx.x;
    const int tid = threadIdx.x;

    if (u < 768) {
        const int lane = tid & 63, wvi = tid >> 6;
        const int l31 = lane & 31, hi = lane >> 5;
        const int m   = u >> 8;
        const int rem = u & 255;
        const int rb0 = (rem & 7) * 128 + wvi * 32;
        const int col = (rem >> 3) * 32 + l31;
        const float* W        = (m == 0) ? Wq : (m == 1) ? Wk : Wv;
        unsigned short* Out   = (m == 0) ? Qb : (m == 1) ? Kb : Vb;
        const float osc = (m == 0) ? 0.12751879523173864f : 1.0f; // 128^-0.5*log2e

        const float* xrow = x + (size_t)(rb0 + l31) * 128 + 8 * hi;
        const float* wrow = W + (size_t)col * 128 + 8 * hi;

        f32x16 acc = {};
        #pragma unroll
        for (int ks = 0; ks < 8; ++ks) {
            float4 xa = *reinterpret_cast<const float4*>(xrow + ks * 16);
            float4 xb = *reinterpret_cast<const float4*>(xrow + ks * 16 + 4);
            float4 wa = *reinterpret_cast<const float4*>(wrow + ks * 16);
            float4 wb = *reinterpret_cast<const float4*>(wrow + ks * 16 + 4);
            union { short8 s8; unsigned uu[4]; } af, bf;
            af.uu[0] = cvt_pk_bf16(xa.x, xa.y); af.uu[1] = cvt_pk_bf16(xa.z, xa.w);
            af.uu[2] = cvt_pk_bf16(xb.x, xb.y); af.uu[3] = cvt_pk_bf16(xb.z, xb.w);
            bf.uu[0] = cvt_pk_bf16(wa.x, wa.y); bf.uu[1] = cvt_pk_bf16(wa.z, wa.w);
            bf.uu[2] = cvt_pk_bf16(wb.x, wb.y); bf.uu[3] = cvt_pk_bf16(wb.z, wb.w);
            acc = __builtin_amdgcn_mfma_f32_32x32x16_bf16(af.s8, bf.s8, acc, 0, 0, 0);
        }
        #pragma unroll
        for (int i = 0; i < 16; ++i) {
            int mm = (i & 3) + 8 * (i >> 2) + 4 * hi;
            Out[(size_t)(rb0 + mm) * DH + col] = f2bf(acc[i] * osc);
        }
    } else if (u < 1792) {
        const int b2 = u - 768;
        const int cb = b2 & 31, rb = b2 >> 5;
        const float L2E = 1.4426950408889634f;
        for (int i = tid; i < 1024; i += 256) {
            int rr = i >> 5, cc = i & 31;
            size_t g = (size_t)(rb * 32 + rr) * 1024 + cb * 32 + cc;
            tile[rr][cc] = (sp[g] + ed[g]) * L2E;
        }
        __syncthreads();
        const int c4l = tid >> 5, rr = tid & 31;
        float4 v = make_float4(tile[rr][4 * c4l + 0], tile[rr][4 * c4l + 1],
                               tile[rr][4 * c4l + 2], tile[rr][4 * c4l + 3]);
        reinterpret_cast<float4*>(Bq)[(size_t)(cb * 8 + c4l) * 1024 + rb * 32 + rr] = v;
    } else {
        const int b2 = u - 1792;                   // 0..31
        const size_t base = (size_t)b2 * 4096 + (size_t)tid * 16;
        #pragma unroll
        for (int t = 0; t < 4; ++t) {
            float4 w = *reinterpret_cast<const float4*>(Wo + base + t * 4);
            float ww[4] = { w.x, w.y, w.z, w.w };
            unsigned short h4[4], l4[4];
            #pragma unroll
            for (int j = 0; j < 4; ++j) {
                unsigned uv = __float_as_uint(ww[j]);
                h4[j] = (unsigned short)(uv >> 16);
                l4[j] = f2bf(ww[j] - __uint_as_float(uv & 0xFFFF0000u));
            }
            *reinterpret_cast<uint2*>(Woh + base + t * 4) = *reinterpret_cast<uint2*>(h4);
            *reinterpret_cast<uint2*>(Wol + base + t * 4) = *reinterpret_cast<uint2*>(l4);
        }
    }
}

// ---------------------------------------------------------------------------
// helpers
// ---------------------------------------------------------------------------
static __device__ __forceinline__ void stage_vt(const unsigned short* __restrict__ src,
                                                char* base, int tid) {
    #pragma unroll
    for (int it = 0; it < 2; ++it) {
        int pr = it * 256 + tid;
        short8 v0 = *reinterpret_cast<const short8*>(src + (size_t)(2 * pr) * 8);
        short8 v1 = *reinterpret_cast<const short8*>(src + (size_t)(2 * pr + 1) * 8);
        #pragma unroll
        for (int h = 0; h < 8; ++h) {
            unsigned d = (unsigned)(unsigned short)v0[h] |
                         ((unsigned)(unsigned short)v1[h] << 16);
            *reinterpret_cast<unsigned*>(base + h * 2048 + ((4 * pr) ^ (h << 4))) = d;
        }
    }
    reinterpret_cast<unsigned*>(base + 16384)[tid]       = 0x3F803F80u; // ones row
    reinterpret_cast<unsigned*>(base + 16384)[tid + 256] = 0x3F803F80u;
}

static __device__ __forceinline__ f32x16 load_bias16(const float4* bq4, int cbv) {
    const float4* b = bq4 + (size_t)cbv * 8192;
    float4 b0 = b[0], b1 = b[2048], b2 = b[4096], b3 = b[6144];
    f32x16 o;
    o[0]  = b0.x; o[1]  = b0.y; o[2]  = b0.z; o[3]  = b0.w;
    o[4]  = b1.x; o[5]  = b1.y; o[6]  = b1.z; o[7]  = b1.w;
    o[8]  = b2.x; o[9]  = b2.y; o[10] = b2.z; o[11] = b2.w;
    o[12] = b3.x; o[13] = b3.y; o[14] = b3.z; o[15] = b3.w;
    return o;
}

static __device__ __forceinline__ void attn_step(int cbv, const f32x16& bias,
                                                 const short8& kfv, const short8& qfv,
                                                 const char* vbs, int vswz, int hi,
                                                 f32x16& oacc) {
    f32x16 sf = bias;   // C-init = bias: S*scale+B computed inside the MFMA
    sf = __builtin_amdgcn_mfma_f32_32x32x16_bf16(kfv, qfv, sf, 0, 0, 0);
    float p[16];
    #pragma unroll
    for (int i = 0; i < 16; ++i) p[i] = fast_exp2(sf[i]);
    unsigned u0 = cvt_pk_bf16(p[0],  p[1]);
    unsigned u1 = cvt_pk_bf16(p[2],  p[3]);
    unsigned u2 = cvt_pk_bf16(p[4],  p[5]);
    unsigned u3 = cvt_pk_bf16(p[6],  p[7]);
    unsigned u4 = cvt_pk_bf16(p[8],  p[9]);
    unsigned u5 = cvt_pk_bf16(p[10], p[11]);
    unsigned u6 = cvt_pk_bf16(p[12], p[13]);
    unsigned u7 = cvt_pk_bf16(p[14], p[15]);
    permlane32_swap(u0, u2);
    permlane32_swap(u1, u3);
    permlane32_swap(u4, u6);
    permlane32_swap(u5, u7);
    union { short8 s8; unsigned uu[4]; } pb1, pb2;
    pb1.uu[0] = u0; pb1.uu[1] = u1; pb1.uu[2] = u2; pb1.uu[3] = u3;
    pb2.uu[0] = u4; pb2.uu[1] = u5; pb2.uu[2] = u6; pb2.uu[3] = u7;

    short8 vf1 = *reinterpret_cast<const short8*>(vbs + ((cbv * 64 + 16 * hi)      ^ vswz));
    short8 vf2 = *reinterpret_cast<const short8*>(vbs + ((cbv * 64 + 32 + 16 * hi) ^ vswz));
    oacc = __builtin_amdgcn_mfma_f32_32x32x16_bf16(vf1, pb1.s8, oacc, 0, 0, 0);
    oacc = __builtin_amdgcn_mfma_f32_32x32x16_bf16(vf2, pb2.s8, oacc, 0, 0, 0);
}

static __device__ __forceinline__ void attn_epilogue(const f32x16& oa, int dd, int r, int hi,
                                                     unsigned short* __restrict__ Oh,
                                                     unsigned short* __restrict__ Ol) {
    // With min-clamped V rows, A-rows 8..31 are ALL ones, so D rows 8..31
    // each hold the full lsum. Every lane's own oa[4] (row 8 for hi=0,
    // row 12 for hi=1) is therefore already the complete sum.
    const float ls = oa[4];
    const float rl = 1.f / ls;
    unsigned short h4[4], l4[4];
    #pragma unroll
    for (int i = 0; i < 4; ++i) {
        float v = oa[i] * rl;
        unsigned uv = __float_as_uint(v);
        h4[i] = (unsigned short)(uv >> 16);
        l4[i] = f2bf(v - __uint_as_float(uv & 0xFFFF0000u));
    }
    size_t off = (size_t)dd * 8192 + (size_t)r * 8 + 4 * hi;
    *reinterpret_cast<uint2*>(Oh + off) = *reinterpret_cast<uint2*>(h4);
    *reinterpret_cast<uint2*>(Ol + off) = *reinterpret_cast<uint2*>(l4);
}

// ---------------------------------------------------------------------------
// Kernel 2: attention, 2 slices/block at FULL columns, bias registers shared
// across slices (bias L2 traffic 512->256 MB), no combine pass.
// Grid 512 blocks (rbx = bid&7 keeps bias-sharing blocks on one XCD).
// LDS 36.9 KB (2 x 9x1024 bf16 V^T, swizzled, + ones rows).
// ---------------------------------------------------------------------------
__global__ __launch_bounds__(256) void attn2_kernel(
        const unsigned short* __restrict__ Qb, const unsigned short* __restrict__ Kb,
        const unsigned short* __restrict__ Vb, const float* __restrict__ Bq,
        unsigned short* __restrict__ Oh, unsigned short* __restrict__ Ol) {
    __shared__ __align__(16) char smraw[36864];
    const int un = blockIdx.x, tid = threadIdx.x;
    const int rbx = un & 7, dp = un >> 3;
    const int lane = tid & 63, wvi = tid >> 6;
    const int l31 = lane & 31, hi = lane >> 5;

    stage_vt(Vb + (size_t)(2 * dp) * 8192,     smraw,         tid);
    stage_vt(Vb + (size_t)(2 * dp + 1) * 8192, smraw + 18432, tid);
    __syncthreads();

    const int r = rbx * 128 + wvi * 32 + l31;
    short8 qf0 = {}, qf1 = {};
    if (!hi) {
        qf0 = *reinterpret_cast<const short8*>(Qb + (size_t)(2 * dp)     * 8192 + (size_t)r * 8);
        qf1 = *reinterpret_cast<const short8*>(Qb + (size_t)(2 * dp + 1) * 8192 + (size_t)r * 8);
    }
    f32x16 o0 = {}, o1 = {};
    const unsigned short* kp0 = Kb + (size_t)(2 * dp) * 8192 + (size_t)l31 * 8;
    const unsigned short* kp1 = kp0 + 8192;
    const float4* bq4 = reinterpret_cast<const float4*>(Bq) + (size_t)hi * 1024 + r;
    const int vrow = (l31 < 8) ? l31 : 8;          // lanes 8..31 -> ones row
    const char* vb0 = smraw + vrow * 2048;
    const char* vb1 = smraw + 18432 + vrow * 2048;
    const int vswz = vrow << 4;

    f32x16 bA = load_bias16(bq4, 0), bB = load_bias16(bq4, 1);
    short8 kA0 = *reinterpret_cast<const short8*>(kp0);
    short8 kA1 = *reinterpret_cast<const short8*>(kp1);
    short8 kB0 = *reinterpret_cast<const short8*>(kp0 + 256);
    short8 kB1 = *reinterpret_cast<const short8*>(kp1 + 256);
    for (int cb = 0; cb < 32; cb += 2) {
        attn_step(cb, bA, kA0, qf0, vb0, vswz, hi, o0);
        attn_step(cb, bA, kA1, qf1, vb1, vswz, hi, o1);
        if (cb < 30) {
            bA = load_bias16(bq4, cb + 2);
            kA0 = *reinterpret_cast<const short8*>(kp0 + (size_t)(cb + 2) * 256);
            kA1 = *reinterpret_cast<const short8*>(kp1 + (size_t)(cb + 2) * 256);
        }
        attn_step(cb + 1, bB, kB0, qf0, vb0, vswz, hi, o0);
        attn_step(cb + 1, bB, kB1, qf1, vb1, vswz, hi, o1);
        if (cb < 30) {
            bB = load_bias16(bq4, cb + 3);
            kB0 = *reinterpret_cast<const short8*>(kp0 + (size_t)(cb + 3) * 256);
            kB1 = *reinterpret_cast<const short8*>(kp1 + (size_t)(cb + 3) * 256);
        }
    }
    attn_epilogue(o0, 2 * dp,     r, hi, Oh, Ol);
    attn_epilogue(o1, 2 * dp + 1, r, hi, Oh, Ol);
}

// ---------------------------------------------------------------------------
// Kernel 3: output projection, 16x16 MFMA, pre-split Wo (R7-proven).
// ---------------------------------------------------------------------------
__global__ __launch_bounds__(256) void oproj_kernel(
        const unsigned short* __restrict__ Oh, const unsigned short* __restrict__ Ol,
        const unsigned short* __restrict__ Woh, const unsigned short* __restrict__ Wol,
        float* __restrict__ out) {
    __shared__ float red[4][256];
    const int u = blockIdx.x, tid = threadIdx.x;
    const int lane = tid & 63, wvi = tid >> 6;
    const int l15 = lane & 15, kg = lane >> 4;
    const int rbase = (u & 63) * 16, cbase = (u >> 6) * 16;

    const unsigned short* ah_p = Oh  + (size_t)(rbase + l15) * 1024 + wvi * 256 + kg * 8;
    const unsigned short* al_p = Ol  + (size_t)(rbase + l15) * 1024 + wvi * 256 + kg * 8;
    const unsigned short* bh_p = Woh + (size_t)(cbase + l15) * 1024 + wvi * 256 + kg * 8;
    const unsigned short* bl_p = Wol + (size_t)(cbase + l15) * 1024 + wvi * 256 + kg * 8;

    f32x4 acc = {};
    #pragma unroll
    for (int ks = 0; ks < 8; ++ks) {
        short8 ah = *reinterpret_cast<const short8*>(ah_p + ks * 32);
        short8 al = *reinterpret_cast<const short8*>(al_p + ks * 32);
        short8 bh = *reinterpret_cast<const short8*>(bh_p + ks * 32);
        short8 bl = *reinterpret_cast<const short8*>(bl_p + ks * 32);
        acc = __builtin_amdgcn_mfma_f32_16x16x32_bf16(ah, bh, acc, 0, 0, 0);
        acc = __builtin_amdgcn_mfma_f32_16x16x32_bf16(al, bh, acc, 0, 0, 0);
        acc = __builtin_amdgcn_mfma_f32_16x16x32_bf16(ah, bl, acc, 0, 0, 0);
    }
    #pragma unroll
    for (int i = 0; i < 4; ++i)
        red[wvi][(kg * 4 + i) * 16 + l15] = acc[i];
    __syncthreads();
    float v = red[0][tid & 255] + red[1][tid & 255] + red[2][tid & 255] + red[3][tid & 255];
    out[(size_t)(rbase + (tid >> 4)) * D_DIM + cbase + (tid & 15)] = v;
}

// ---------------------------------------------------------------------------
extern "C" void kernel_launch(void* const* d_in, const int* in_sizes, int n_in,
                              void* d_out, int out_size, void* d_ws, size_t ws_size,
                              hipStream_t stream) {
    const float* x  = (const float*)d_in[0];
    const float* sp = (const float*)d_in[1];
    const float* ed = (const float*)d_in[2];
    const float* Wq = (const float*)d_in[3];
    const float* Wk = (const float*)d_in[4];
    const float* Wv = (const float*)d_in[5];
    const float* Wo = (const float*)d_in[6];
    float* out = (float*)d_out;

    float* ws = (float*)d_ws;
    const size_t M = (size_t)N_NODES * DH;             // 1M elements
    float* Bq = ws;                                    // 4 MB f32 (fragment-order)
    unsigned short* Qb = (unsigned short*)(ws + M);    // 2 MB bf16 each
    unsigned short* Kb = Qb + M;
    unsigned short* Vb = Kb + M;
    unsigned short* Oh = Vb + M;                       // attn out, hi/lo bf16
    unsigned short* Ol = Oh + M;
    unsigned short* Woh = Ol + M;                      // 128x1024 bf16 each
    unsigned short* Wol = Woh + 131072;                // total ~14.5 MB

    prep_kernel<<<dim3(1824), 256, 0, stream>>>(x, Wq, Wk, Wv, sp, ed, Wo,
                                                Qb, Kb, Vb, Bq, Woh, Wol);
    attn2_kernel<<<dim3(512), 256, 0, stream>>>(Qb, Kb, Vb, Bq, Oh, Ol);
    oproj_kernel<<<dim3(512), 256, 0, stream>>>(Oh, Ol, Woh, Wol, out);
}